// Round 6
// baseline (255.315 us; speedup 1.0000x reference)
//
#include <hip/hip_runtime.h>

#define T_TERMS 768
#define NV 6
#define D1 5
#define D2 9
#define T2 (T_TERMS * T_TERMS)                 // 589824
#define PTOT (T2 + T_TERMS + 1)                // 590593
#define NROWS ((unsigned int)PTOT * NV)        // 3,543,558 rows per tensor
#define NOUT (NROWS * (unsigned int)D2)        // 31,892,022 f32 per tensor (== 2 mod 4!)
#define BLK_DW (256u * D2)                     // 2304 dwords per full block

typedef float f4 __attribute__((ext_vector_type(4)));
typedef float f4u __attribute__((ext_vector_type(4), aligned(4)));
typedef float f2 __attribute__((ext_vector_type(2)));

// Kernel 1: per-tensor interval bound. block 0: l from under (sum of per-term
// interval-product lows), block 1: u from over (sum of highs).
__global__ void bounds_kernel(const float* __restrict__ Pu,
                              const float* __restrict__ Po,
                              float* __restrict__ ws) {
    const float* __restrict__ P = blockIdx.x ? Po : Pu;
    int t = threadIdx.x;
    float acc = 0.f;
    if (t < T_TERMS) {
        f2 r[15];
        const f2* p2 = (const f2*)(P + t * (NV * D1));
        #pragma unroll
        for (int i = 0; i < 15; ++i) r[i] = p2[i];
        const float* rf = (const float*)r;
        float clo = 1.f, chi = 1.f;
        #pragma unroll
        for (int v = 0; v < NV; ++v) {
            float lo = rf[v * 5 + 0], hi = lo;
            #pragma unroll
            for (int i = 1; i < 5; ++i) {
                float x = rf[v * 5 + i];
                lo = fminf(lo, x); hi = fmaxf(hi, x);
            }
            float a = clo * lo, b = clo * hi, c = chi * lo, d = chi * hi;
            clo = fminf(fminf(a, b), fminf(c, d));
            chi = fmaxf(fmaxf(a, b), fmaxf(c, d));
        }
        acc = blockIdx.x ? chi : clo;
    }
    __shared__ float sred[12];
    for (int off = 32; off; off >>= 1) acc += __shfl_down(acc, off);
    int wave = threadIdx.x >> 6;
    if ((threadIdx.x & 63) == 0) sred[wave] = acc;
    __syncthreads();
    if (threadIdx.x == 0) {
        float s = 0.f;
        #pragma unroll
        for (int w = 0; w < 12; ++w) s += sred[w];
        ws[blockIdx.x] = s;   // ws[0]=l, ws[1]=u
    }
}

// Kernel 1b: relu relaxation coefficients from (l,u). coef = ws+2.
__global__ void coef_kernel(float* __restrict__ ws) {
    float l = ws[0], u = ws[1];
    float den = (u - l > 0.f) ? (u - l) : 1.f;
    float au, bu, cu, ao, bo, co;
    if (l >= 0.f) {
        au = 0.f; bu = 1.f; cu = 0.f;
        ao = 0.f; bo = 1.f; co = 0.f;
    } else if (u <= 0.f) {
        au = bu = cu = 0.f;
        ao = bo = co = 0.f;
    } else {
        au = 1.f / den; bu = -l / den; cu = 0.f;
        float d2 = den * den;
        ao = u / d2; bo = -2.f * u * l / d2; co = u * l * l / d2;
    }
    float* coef = ws + 2;
    coef[0] = au; coef[1] = bu; coef[2] = cu;
    coef[3] = ao; coef[4] = bo; coef[5] = co;
}

// Kernel 2: one thread per output ROW (9 coeffs); LDS-staged coalesced stores.
// ten=1 ("over") output base is offset NOUT dwords == 2 (mod 4) -> its quad
// stores must be re-aligned: peel 2 head + 2 tail dwords, 575 aligned quads.
__global__ __launch_bounds__(256) void expand_kernel(
        const float* __restrict__ Pu,
        const float* __restrict__ Po,
        const float* __restrict__ coef,
        float* __restrict__ out) {
    __shared__ float lds[BLK_DW];   // 9216 B
    static constexpr float Wt[5][5] = {
        {1.0f,        4.0f/8.0f,   6.0f/28.0f,  4.0f/56.0f,  1.0f/70.0f},
        {4.0f/8.0f,   16.0f/28.0f, 24.0f/56.0f, 16.0f/70.0f, 4.0f/56.0f},
        {6.0f/28.0f,  24.0f/56.0f, 36.0f/70.0f, 24.0f/56.0f, 6.0f/28.0f},
        {4.0f/56.0f,  16.0f/70.0f, 24.0f/56.0f, 16.0f/28.0f, 4.0f/8.0f},
        {1.0f/70.0f,  4.0f/56.0f,  6.0f/28.0f,  4.0f/8.0f,   1.0f}
    };

    const unsigned tid = threadIdx.x;
    const unsigned bid = blockIdx.x;
    const unsigned ten = blockIdx.y;          // 0 = under, 1 = over
    const float* __restrict__ P = ten ? Po : Pu;
    const float* __restrict__ c3 = coef + ten * 3;

    const unsigned rr = bid * 256u + tid;
    const unsigned nvalid = min(256u, NROWS - bid * 256u);

    float c[9] = {0.f,0.f,0.f,0.f,0.f,0.f,0.f,0.f,0.f};
    if (rr < NROWS) {
        unsigned p = rr / 6u;
        unsigned v = rr - p * 6u;
        f4 a4; float a1;
        f4 b4; float b1;
        float scale = 1.f;
        if (p < (unsigned)T2) {
            unsigned t = p / (unsigned)T_TERMS;
            unsigned s = p - t * (unsigned)T_TERMS;
            const float* A = P + (t * NV + v) * D1;
            const float* B = P + (s * NV + v) * D1;
            a4 = *(const f4u*)A;  a1 = A[4];
            b4 = *(const f4u*)B;  b1 = B[4];
            if (v == 0u) scale = c3[0];
        } else if (p < (unsigned)(T2 + T_TERMS)) {
            unsigned t = p - (unsigned)T2;
            const float* A = P + (t * NV + v) * D1;
            a4 = *(const f4u*)A;  a1 = A[4];
            b4 = (f4){1.f,1.f,1.f,1.f};  b1 = 1.f;
            if (v == 0u) scale = c3[1];
        } else {
            a4 = (f4){1.f,1.f,1.f,1.f};  a1 = 1.f;
            b4 = (f4){1.f,1.f,1.f,1.f};  b1 = 1.f;
            if (v == 0u) scale = c3[2];
        }
        float a[5] = {a4.x * scale, a4.y * scale, a4.z * scale, a4.w * scale, a1 * scale};
        float b[5] = {b4.x, b4.y, b4.z, b4.w, b1};
        #pragma unroll
        for (int i = 0; i < 5; ++i)
            #pragma unroll
            for (int j = 0; j < 5; ++j)
                c[i + j] = fmaf(Wt[i][j] * a[i], b[j], c[i + j]);
    }
    #pragma unroll
    for (int k = 0; k < 9; ++k) lds[tid * 9u + k] = c[k];   // stride 9: 2-way, free
    __syncthreads();

    if (nvalid == 256u) {
        if (ten == 0u) {
            // base dword offset bid*2304 ≡ 0 (mod 4): straight aligned quads
            const f4* l4 = (const f4*)lds;
            f4* o4 = (f4*)(out + (size_t)bid * BLK_DW);
            o4[tid]        = l4[tid];
            o4[tid + 256u] = l4[tid + 256u];
            if (tid < 64u) o4[tid + 512u] = l4[tid + 512u];
        } else {
            // base = out + NOUT + bid*2304 dwords; NOUT ≡ 2 (mod 4) -> +2 dwords realigns
            float* ob = out + (size_t)NOUT + (size_t)bid * BLK_DW;
            if (tid < 2u)  ob[tid] = lds[tid];                       // head dwords 0..1
            if (tid >= 2u && tid < 4u)
                ob[2300u + tid] = lds[2300u + tid];                  // tail dwords 2302..2303
            const f2* l2 = (const f2*)lds;                           // 8B-aligned LDS reads
            #pragma unroll 1
            for (unsigned q = tid; q < 575u; q += 256u) {
                f2 x = l2[1u + 2u * q];
                f2 y = l2[2u + 2u * q];
                f4 vv; vv.x = x.x; vv.y = x.y; vv.z = y.x; vv.w = y.y;
                *(f4*)(ob + 2u + 4u * q) = vv;                       // 16B-aligned global
            }
        }
    } else {
        float* o = out + (size_t)ten * NOUT + (size_t)bid * BLK_DW;
        const unsigned nd = nvalid * 9u;
        for (unsigned x = tid; x < nd; x += 256u)
            o[x] = lds[x];
    }
}

extern "C" void kernel_launch(void* const* d_in, const int* in_sizes, int n_in,
                              void* d_out, int out_size, void* d_ws, size_t ws_size,
                              hipStream_t stream) {
    const float* Pu = (const float*)d_in[0];
    const float* Po = (const float*)d_in[1];
    float* ws = (float*)d_ws;
    float* out = (float*)d_out;

    bounds_kernel<<<2, 768, 0, stream>>>(Pu, Po, ws);
    coef_kernel<<<1, 1, 0, stream>>>(ws);

    unsigned int blocks_x = (NROWS + 255u) / 256u;   // 13843
    dim3 grid(blocks_x, 2, 1);
    expand_kernel<<<grid, 256, 0, stream>>>(Pu, Po, ws + 2, out);
}